// Round 9
// baseline (1331.829 us; speedup 1.0000x reference)
//
#include <hip/hip_runtime.h>
#include <cmath>

#define NB 32
#define CH 384
#define IH 64
#define IW 64
#define OH 32
#define OW 32
#define PR 70    // padded rows: iy -3..66 -> pr 0..69
#define PWQ 18   // quad-split width: padded col c -> class (c&3), quad (c>>2)

// ---------------------------------------------------------------------------
// Single fused kernel, one 128-thread block per (n,c) plane.
// Block order: blocks 32c..32c+31 cover channel c (contiguous -> any resident
// dispatch window contains complete channels -> spin cannot deadlock).
// Phase 1: quad-split LDS stage, 7x7 + 3x3 stride-2 depthwise conv, outputs
//          kept in fp32 registers; per-wave stats -> partial slab (plain
//          stores, no atomics), release-increment per-channel counter.
// Phase 2: tid0 acquire-spins until counter[c]==32; wave 0 reduces the 64
//          partial float4s (agent-scope loads), folds BN -> params in LDS;
//          all threads apply affine+add+exact GELU from registers, store.
// ---------------------------------------------------------------------------
__global__ __launch_bounds__(128, 4) void fused_kernel(
    const float* __restrict__ x,
    const float* __restrict__ w_lk,
    const float* __restrict__ w_sk,
    const float* __restrict__ gamma_lk, const float* __restrict__ beta_lk,
    const float* __restrict__ gamma_sk, const float* __restrict__ beta_sk,
    int*   __restrict__ cnt,        // [CH], zeroed per call
    float* __restrict__ partial,    // [CH][NB][2][4]
    float* __restrict__ out)
{
    __shared__ float sxq[4][PR][PWQ];
    __shared__ float sp[4];

    const int b   = blockIdx.x;
    const int c   = b >> 5;          // channel (blocks contiguous per channel)
    const int n   = b & (NB - 1);
    const int pl  = n * CH + c;      // plane index in NCHW
    const int tid = threadIdx.x;

    // ---- zero halo only (interior fully overwritten by staging) ----
    for (int i = tid; i < 4 * 3 * PWQ; i += 128) {
        const int f = i / (3 * PWQ);
        const int rem = i % (3 * PWQ);
        const int r = rem / PWQ, q = rem % PWQ;
        sxq[f][r][q] = 0.0f;
        sxq[f][67 + r][q] = 0.0f;
    }
    for (int i = tid; i < 64 * 6; i += 128) {
        const int r = 3 + i / 6;
        const int t = i % 6;
        const int f = (t < 3) ? t : ((t == 3) ? 3 : t - 4);
        const int q = (t < 3) ? 0 : ((t == 3) ? 16 : 17);
        sxq[f][r][q] = 0.0f;
    }

    // ---- stage plane (float4), scatter into quad classes ----
    const float4* xp4 = (const float4*)(x + (size_t)pl * (IH * IW));
#pragma unroll
    for (int it = 0; it < 8; ++it) {
        const int i = tid + it * 128;
        const float4 v = xp4[i];
        const int r  = (i >> 4) + 3;
        const int q4 = i & 15;
        sxq[3][r][q4]     = v.x;     // cp = 4q4+3: class 3, quad q4
        sxq[0][r][q4 + 1] = v.y;     // cp = 4q4+4: class 0, quad q4+1
        sxq[1][r][q4 + 1] = v.z;     // cp = 4q4+5: class 1, quad q4+1
        sxq[2][r][q4 + 1] = v.w;     // cp = 4q4+6: class 2, quad q4+1
    }
    __syncthreads();

    // per-channel weights (block-uniform -> scalar loads)
    float wl[49], ws9[9];
#pragma unroll
    for (int t = 0; t < 49; ++t) wl[t] = w_lk[c * 49 + t];
#pragma unroll
    for (int t = 0; t < 9; ++t)  ws9[t] = w_sk[c * 9 + t];

    const int lane = tid & 63;
    const int wv   = tid >> 6;         // 0..1
    const int j16  = lane & 15;        // col-pair index; qb = j16
    const int g    = lane >> 4;        // 0..3 row group
    const int qb   = j16;
    const int oy0  = (wv * 4 + g) * 4; // output rows oy0..oy0+3
    const int prb  = 2 * oy0;

    float alA[4] = {0.f,0.f,0.f,0.f}, alB[4] = {0.f,0.f,0.f,0.f};
    float asA[4] = {0.f,0.f,0.f,0.f}, asB[4] = {0.f,0.f,0.f,0.f};

#pragma unroll
    for (int k = 0; k < 13; ++k) {
        const int pr = prb + k;
        const float E0 = sxq[0][pr][qb];
        const float E1 = sxq[0][pr][qb + 1];
        const float E2 = sxq[0][pr][qb + 2];
        const float F0 = sxq[1][pr][qb];
        const float F1 = sxq[1][pr][qb + 1];
        const float G0 = sxq[2][pr][qb];
        const float G1 = sxq[2][pr][qb + 1];
        const float H0 = sxq[3][pr][qb];
        const float H1 = sxq[3][pr][qb + 1];
#pragma unroll
        for (int j = 0; j < 4; ++j) {
            if (k >= 2 * j && k <= 2 * j + 6) {        // folds at compile time
                const int ky = k - 2 * j;
                alA[j] = fmaf(E0, wl[ky * 7 + 0], alA[j]);
                alA[j] = fmaf(F0, wl[ky * 7 + 1], alA[j]);
                alA[j] = fmaf(G0, wl[ky * 7 + 2], alA[j]);
                alA[j] = fmaf(H0, wl[ky * 7 + 3], alA[j]);
                alA[j] = fmaf(E1, wl[ky * 7 + 4], alA[j]);
                alA[j] = fmaf(F1, wl[ky * 7 + 5], alA[j]);
                alA[j] = fmaf(G1, wl[ky * 7 + 6], alA[j]);
                alB[j] = fmaf(G0, wl[ky * 7 + 0], alB[j]);
                alB[j] = fmaf(H0, wl[ky * 7 + 1], alB[j]);
                alB[j] = fmaf(E1, wl[ky * 7 + 2], alB[j]);
                alB[j] = fmaf(F1, wl[ky * 7 + 3], alB[j]);
                alB[j] = fmaf(G1, wl[ky * 7 + 4], alB[j]);
                alB[j] = fmaf(H1, wl[ky * 7 + 5], alB[j]);
                alB[j] = fmaf(E2, wl[ky * 7 + 6], alB[j]);
            }
            if (k >= 2 * j + 2 && k <= 2 * j + 4) {
                const int kys = k - 2 * j - 2;
                asA[j] = fmaf(G0, ws9[kys * 3 + 0], asA[j]);
                asA[j] = fmaf(H0, ws9[kys * 3 + 1], asA[j]);
                asA[j] = fmaf(E1, ws9[kys * 3 + 2], asA[j]);
                asB[j] = fmaf(E1, ws9[kys * 3 + 0], asB[j]);
                asB[j] = fmaf(F1, ws9[kys * 3 + 1], asB[j]);
                asB[j] = fmaf(G1, ws9[kys * 3 + 2], asB[j]);
            }
        }
    }

    // per-thread stats, wave64 reduce, lane 0 publishes wave partial
    float s0 = 0.f, s1 = 0.f, s2 = 0.f, s3 = 0.f;
#pragma unroll
    for (int j = 0; j < 4; ++j) {
        s0 += alA[j] + alB[j];
        s1 += alA[j] * alA[j] + alB[j] * alB[j];
        s2 += asA[j] + asB[j];
        s3 += asA[j] * asA[j] + asB[j] * asB[j];
    }
#pragma unroll
    for (int off = 32; off >= 1; off >>= 1) {
        s0 += __shfl_down(s0, off);
        s1 += __shfl_down(s1, off);
        s2 += __shfl_down(s2, off);
        s3 += __shfl_down(s3, off);
    }
    if (lane == 0) {
        ((float4*)partial)[(c * NB + n) * 2 + wv] = make_float4(s0, s1, s2, s3);
        __threadfence();             // flush partial device-wide
    }
    __syncthreads();
    if (tid == 0) {
        __hip_atomic_fetch_add(&cnt[c], 1, __ATOMIC_RELEASE,
                               __HIP_MEMORY_SCOPE_AGENT);
        while (__hip_atomic_load(&cnt[c], __ATOMIC_ACQUIRE,
                                 __HIP_MEMORY_SCOPE_AGENT) < NB)
            __builtin_amdgcn_s_sleep(2);
    }
    __syncthreads();

    // ---- phase 2: reduce this channel's 64 wave-partials (wave 0) ----
    if (tid < 64) {
        const float* pp = partial + (size_t)c * (NB * 2 * 4) + tid * 4;
        float t0 = __hip_atomic_load(pp + 0, __ATOMIC_RELAXED, __HIP_MEMORY_SCOPE_AGENT);
        float t1 = __hip_atomic_load(pp + 1, __ATOMIC_RELAXED, __HIP_MEMORY_SCOPE_AGENT);
        float t2 = __hip_atomic_load(pp + 2, __ATOMIC_RELAXED, __HIP_MEMORY_SCOPE_AGENT);
        float t3 = __hip_atomic_load(pp + 3, __ATOMIC_RELAXED, __HIP_MEMORY_SCOPE_AGENT);
#pragma unroll
        for (int off = 32; off >= 1; off >>= 1) {
            t0 += __shfl_down(t0, off);
            t1 += __shfl_down(t1, off);
            t2 += __shfl_down(t2, off);
            t3 += __shfl_down(t3, off);
        }
        if (tid == 0) {
            const float inv_cnt = 1.0f / (float)(NB * OH * OW);
            const float mean_l = t0 * inv_cnt;
            const float var_l  = t1 * inv_cnt - mean_l * mean_l;
            const float sc_l   = gamma_lk[c] * rsqrtf(var_l + 1e-5f);
            const float sh_l   = beta_lk[c] - mean_l * sc_l;
            const float mean_s = t2 * inv_cnt;
            const float var_s  = t3 * inv_cnt - mean_s * mean_s;
            const float sc_s   = gamma_sk[c] * rsqrtf(var_s + 1e-5f);
            const float sh_s   = beta_sk[c] - mean_s * sc_s;
            sp[0] = sc_l; sp[1] = sh_l; sp[2] = sc_s; sp[3] = sh_s;
        }
    }
    __syncthreads();

    const float sc_l = sp[0], sh_l = sp[1], sc_s = sp[2], sh_s = sp[3];

    // ---- apply affine + add + exact GELU from registers, store ----
    float* op = out + (size_t)pl * (OH * OW);
#pragma unroll
    for (int j = 0; j < 4; ++j) {
        const float vA = fmaf(alA[j], sc_l, sh_l) + fmaf(asA[j], sc_s, sh_s);
        const float vB = fmaf(alB[j], sc_l, sh_l) + fmaf(asB[j], sc_s, sh_s);
        float2 r;
        r.x = 0.5f * vA * (1.0f + erff(vA * 0.70710678118654752f));
        r.y = 0.5f * vB * (1.0f + erff(vB * 0.70710678118654752f));
        *(float2*)(op + (oy0 + j) * OW + 2 * j16) = r;
    }
}

extern "C" void kernel_launch(void* const* d_in, const int* in_sizes, int n_in,
                              void* d_out, int out_size, void* d_ws, size_t ws_size,
                              hipStream_t stream) {
    const float* x        = (const float*)d_in[0];
    const float* w_lk     = (const float*)d_in[1];
    const float* gamma_lk = (const float*)d_in[2];
    const float* beta_lk  = (const float*)d_in[3];
    const float* w_sk     = (const float*)d_in[4];
    const float* gamma_sk = (const float*)d_in[5];
    const float* beta_sk  = (const float*)d_in[6];
    float* out = (float*)d_out;

    int*   cnt     = (int*)d_ws;                 // CH ints (1.5 KB)
    float* partial = (float*)d_ws + CH;          // CH*NB*2*4 floats (393 KB)

    hipMemsetAsync(cnt, 0, CH * sizeof(int), stream);

    fused_kernel<<<NB * CH, 128, 0, stream>>>(
        x, w_lk, w_sk, gamma_lk, beta_lk, gamma_sk, beta_sk,
        cnt, partial, out);
}

// Round 10
// 60.793 us; speedup vs baseline: 21.9075x; 21.9075x over previous
//
#include <hip/hip_runtime.h>
#include <hip/hip_fp16.h>
#include <cmath>

#define NB 32
#define CH 384
#define IH 64
#define IW 64
#define OH 32
#define OW 32
#define PR 70    // padded rows: iy -3..66 -> pr 0..69
#define PWQ 18   // quad-split width: padded col c -> class (c&3), quad (c>>2)

typedef unsigned int u32x4 __attribute__((ext_vector_type(4)));
typedef float        f32x4 __attribute__((ext_vector_type(4)));

// ---------------------------------------------------------------------------
// Pass 1: 7x7 + 3x3 depthwise conv (stride 2), one 128-thread block per
// (n,c) plane. Quad-split LDS: sxq[class][row][quad], class = padded_col & 3.
// Thread = 4-row x 2-col output tile (8 px): 13 rows x 9 b32 reads, 2-way
// bank aliased (free). Global loads issued into registers BEFORE halo-zero
// LDS writes (latency hidden under halo work).
// Outputs packed half2{y_lk,y_sk}; per-wave stats written NON-atomically to
// a partials slab (every slot written every call -> no memset needed).
// ---------------------------------------------------------------------------
__global__ __launch_bounds__(128, 4) void conv_stats_kernel(
    const float* __restrict__ x,
    const float* __restrict__ w_lk,
    const float* __restrict__ w_sk,
    uint2* __restrict__ yls,        // [planes][OH*OW/2] packed pairs
    float* __restrict__ partial)    // [CH][NB][2][4] per-wave partial sums
{
    __shared__ float sxq[4][PR][PWQ];

    const int nc  = blockIdx.x;
    const int n   = nc / CH;
    const int c   = nc % CH;
    const int tid = threadIdx.x;

    // ---- issue all staging loads first (HBM latency hides under halo) ----
    const float4* xp4 = (const float4*)(x + (size_t)nc * (IH * IW));
    float4 vbuf[8];
#pragma unroll
    for (int it = 0; it < 8; ++it) vbuf[it] = xp4[tid + it * 128];

    // ---- zero halo only (interior fully overwritten by staging) ----
    for (int i = tid; i < 4 * 3 * PWQ; i += 128) {
        const int f = i / (3 * PWQ);
        const int rem = i % (3 * PWQ);
        const int r = rem / PWQ, q = rem % PWQ;
        sxq[f][r][q] = 0.0f;
        sxq[f][67 + r][q] = 0.0f;
    }
    for (int i = tid; i < 64 * 6; i += 128) {
        const int r = 3 + i / 6;
        const int t = i % 6;
        const int f = (t < 3) ? t : ((t == 3) ? 3 : t - 4);
        const int q = (t < 3) ? 0 : ((t == 3) ? 16 : 17);
        sxq[f][r][q] = 0.0f;
    }

    // ---- scatter staged registers into quad classes ----
#pragma unroll
    for (int it = 0; it < 8; ++it) {
        const int i = tid + it * 128;
        const float4 v = vbuf[it];
        const int r  = (i >> 4) + 3;   // 16 float4 per 64-wide row
        const int q4 = i & 15;         // cols 4q4..4q4+3 -> padded 4q4+3..4q4+6
        sxq[3][r][q4]     = v.x;       // cp = 4q4+3: class 3, quad q4
        sxq[0][r][q4 + 1] = v.y;       // cp = 4q4+4: class 0, quad q4+1
        sxq[1][r][q4 + 1] = v.z;       // cp = 4q4+5: class 1, quad q4+1
        sxq[2][r][q4 + 1] = v.w;       // cp = 4q4+6: class 2, quad q4+1
    }
    __syncthreads();

    // per-channel weights (block-uniform -> scalar loads)
    float wl[49], ws9[9];
#pragma unroll
    for (int t = 0; t < 49; ++t) wl[t] = w_lk[c * 49 + t];
#pragma unroll
    for (int t = 0; t < 9; ++t)  ws9[t] = w_sk[c * 9 + t];

    const int lane = tid & 63;
    const int wv   = tid >> 6;        // 0..1
    const int j16  = lane & 15;       // col-pair index; qb = j16
    const int g    = lane >> 4;       // 0..3 row group
    const int qb   = j16;
    const int oy0  = (wv * 4 + g) * 4;// output rows oy0..oy0+3
    const int prb  = 2 * oy0;

    // A = col 2*j16 (padded base 4qb), B = col 2*j16+1 (padded base 4qb+2)
    float alA[4] = {0.f,0.f,0.f,0.f}, alB[4] = {0.f,0.f,0.f,0.f};
    float asA[4] = {0.f,0.f,0.f,0.f}, asB[4] = {0.f,0.f,0.f,0.f};

#pragma unroll
    for (int k = 0; k < 13; ++k) {
        const int pr = prb + k;
        const float E0 = sxq[0][pr][qb];       // padded col 4qb
        const float E1 = sxq[0][pr][qb + 1];   // 4qb+4
        const float E2 = sxq[0][pr][qb + 2];   // 4qb+8
        const float F0 = sxq[1][pr][qb];       // 4qb+1
        const float F1 = sxq[1][pr][qb + 1];   // 4qb+5
        const float G0 = sxq[2][pr][qb];       // 4qb+2
        const float G1 = sxq[2][pr][qb + 1];   // 4qb+6
        const float H0 = sxq[3][pr][qb];       // 4qb+3
        const float H1 = sxq[3][pr][qb + 1];   // 4qb+7
#pragma unroll
        for (int j = 0; j < 4; ++j) {
            if (k >= 2 * j && k <= 2 * j + 6) {        // folds at compile time
                const int ky = k - 2 * j;
                alA[j] = fmaf(E0, wl[ky * 7 + 0], alA[j]);
                alA[j] = fmaf(F0, wl[ky * 7 + 1], alA[j]);
                alA[j] = fmaf(G0, wl[ky * 7 + 2], alA[j]);
                alA[j] = fmaf(H0, wl[ky * 7 + 3], alA[j]);
                alA[j] = fmaf(E1, wl[ky * 7 + 4], alA[j]);
                alA[j] = fmaf(F1, wl[ky * 7 + 5], alA[j]);
                alA[j] = fmaf(G1, wl[ky * 7 + 6], alA[j]);
                alB[j] = fmaf(G0, wl[ky * 7 + 0], alB[j]);
                alB[j] = fmaf(H0, wl[ky * 7 + 1], alB[j]);
                alB[j] = fmaf(E1, wl[ky * 7 + 2], alB[j]);
                alB[j] = fmaf(F1, wl[ky * 7 + 3], alB[j]);
                alB[j] = fmaf(G1, wl[ky * 7 + 4], alB[j]);
                alB[j] = fmaf(H1, wl[ky * 7 + 5], alB[j]);
                alB[j] = fmaf(E2, wl[ky * 7 + 6], alB[j]);
            }
            if (k >= 2 * j + 2 && k <= 2 * j + 4) {
                const int kys = k - 2 * j - 2;
                asA[j] = fmaf(G0, ws9[kys * 3 + 0], asA[j]);
                asA[j] = fmaf(H0, ws9[kys * 3 + 1], asA[j]);
                asA[j] = fmaf(E1, ws9[kys * 3 + 2], asA[j]);
                asB[j] = fmaf(E1, ws9[kys * 3 + 0], asB[j]);
                asB[j] = fmaf(F1, ws9[kys * 3 + 1], asB[j]);
                asB[j] = fmaf(G1, ws9[kys * 3 + 2], asB[j]);
            }
        }
    }

    // store packed fp16 pairs, accumulate per-thread stats
    float s0 = 0.f, s1 = 0.f, s2 = 0.f, s3 = 0.f;
    uint2* yp = yls + (size_t)nc * (OH * OW / 2);
#pragma unroll
    for (int j = 0; j < 4; ++j) {
        const int oy = oy0 + j;
        const __half2 hA = __floats2half2_rn(alA[j], asA[j]);
        const __half2 hB = __floats2half2_rn(alB[j], asB[j]);
        uint2 u;
        u.x = *reinterpret_cast<const unsigned int*>(&hA);
        u.y = *reinterpret_cast<const unsigned int*>(&hB);
        yp[oy * (OW / 2) + j16] = u;
        s0 += alA[j] + alB[j];
        s1 += alA[j] * alA[j] + alB[j] * alB[j];
        s2 += asA[j] + asB[j];
        s3 += asA[j] * asA[j] + asB[j] * asB[j];
    }

    // wave64 reduce, lane 0 writes this wave's partial (no atomics)
#pragma unroll
    for (int off = 32; off >= 1; off >>= 1) {
        s0 += __shfl_down(s0, off);
        s1 += __shfl_down(s1, off);
        s2 += __shfl_down(s2, off);
        s3 += __shfl_down(s3, off);
    }
    if (lane == 0) {
        ((float4*)partial)[(c * NB + n) * 2 + wv] = make_float4(s0, s1, s2, s3);
    }
}

// ---------------------------------------------------------------------------
// Pass 2: one block per (n,c) plane (256 threads = 256 uint4 = 1024 px).
// Wave 0 reduces this channel's 256 partial floats (64 lanes x float4) via
// butterfly shuffles, lane 0 folds BN -> 4 params in LDS; then all threads
// unpack 4 half2 px/uint4, affine both branches, add, exact GELU.
// yls read non-temporally (single use); out stored non-temporally (never
// re-read) -> preserves L3 for x across replays.
// ---------------------------------------------------------------------------
__global__ __launch_bounds__(256) void apply_kernel(
    const u32x4* __restrict__ yls4,
    const float* __restrict__ partial,
    const float* __restrict__ gamma_lk, const float* __restrict__ beta_lk,
    const float* __restrict__ gamma_sk, const float* __restrict__ beta_sk,
    f32x4* __restrict__ out)
{
    __shared__ float sp[4];

    const int b = blockIdx.x;
    const int c = b % CH;
    const int tid = threadIdx.x;

    if (tid < 64) {
        // lane l reads partial[c*256 + 4l .. +3] = one wave-partial float4
        float4 v = ((const float4*)partial)[c * 64 + tid];
        float s0 = v.x, s1 = v.y, s2 = v.z, s3 = v.w;
#pragma unroll
        for (int off = 32; off >= 1; off >>= 1) {
            s0 += __shfl_down(s0, off);
            s1 += __shfl_down(s1, off);
            s2 += __shfl_down(s2, off);
            s3 += __shfl_down(s3, off);
        }
        if (tid == 0) {
            const float inv_cnt = 1.0f / (float)(NB * OH * OW);
            const float mean_l = s0 * inv_cnt;
            const float var_l  = s1 * inv_cnt - mean_l * mean_l;
            const float sc_l   = gamma_lk[c] * rsqrtf(var_l + 1e-5f);
            const float sh_l   = beta_lk[c] - mean_l * sc_l;
            const float mean_s = s2 * inv_cnt;
            const float var_s  = s3 * inv_cnt - mean_s * mean_s;
            const float sc_s   = gamma_sk[c] * rsqrtf(var_s + 1e-5f);
            const float sh_s   = beta_sk[c] - mean_s * sc_s;
            sp[0] = sc_l; sp[1] = sh_l; sp[2] = sc_s; sp[3] = sh_s;
        }
    }
    __syncthreads();

    const float sc_l = sp[0], sh_l = sp[1], sc_s = sp[2], sh_s = sp[3];

    const int i = b * 256 + tid;
    const u32x4 v = __builtin_nontemporal_load(yls4 + i);
    const unsigned int uv0 = v.x, uv1 = v.y, uv2 = v.z, uv3 = v.w;
    const __half2 h0 = *reinterpret_cast<const __half2*>(&uv0);
    const __half2 h1 = *reinterpret_cast<const __half2*>(&uv1);
    const __half2 h2 = *reinterpret_cast<const __half2*>(&uv2);
    const __half2 h3 = *reinterpret_cast<const __half2*>(&uv3);

    const float v0 = fmaf(__low2float(h0), sc_l, sh_l) + fmaf(__high2float(h0), sc_s, sh_s);
    const float v1 = fmaf(__low2float(h1), sc_l, sh_l) + fmaf(__high2float(h1), sc_s, sh_s);
    const float v2 = fmaf(__low2float(h2), sc_l, sh_l) + fmaf(__high2float(h2), sc_s, sh_s);
    const float v3 = fmaf(__low2float(h3), sc_l, sh_l) + fmaf(__high2float(h3), sc_s, sh_s);

    f32x4 r;
    r.x = 0.5f * v0 * (1.0f + erff(v0 * 0.70710678118654752f));
    r.y = 0.5f * v1 * (1.0f + erff(v1 * 0.70710678118654752f));
    r.z = 0.5f * v2 * (1.0f + erff(v2 * 0.70710678118654752f));
    r.w = 0.5f * v3 * (1.0f + erff(v3 * 0.70710678118654752f));
    __builtin_nontemporal_store(r, out + i);
}

extern "C" void kernel_launch(void* const* d_in, const int* in_sizes, int n_in,
                              void* d_out, int out_size, void* d_ws, size_t ws_size,
                              hipStream_t stream) {
    const float* x        = (const float*)d_in[0];
    const float* w_lk     = (const float*)d_in[1];
    const float* gamma_lk = (const float*)d_in[2];
    const float* beta_lk  = (const float*)d_in[3];
    const float* w_sk     = (const float*)d_in[4];
    const float* gamma_sk = (const float*)d_in[5];
    const float* beta_sk  = (const float*)d_in[6];
    float* out = (float*)d_out;

    float* partial = (float*)d_ws;                       // CH*NB*2*4 floats (393 KB)
    uint2* yls     = (uint2*)(partial + CH * NB * 2 * 4);// 50 MB packed fp16 pairs

    conv_stats_kernel<<<NB * CH, 128, 0, stream>>>(x, w_lk, w_sk, yls, partial);
    apply_kernel<<<NB * CH, 256, 0, stream>>>(
        (const u32x4*)yls, partial, gamma_lk, beta_lk, gamma_sk, beta_sk,
        (f32x4*)out);
}